// Round 9
// baseline (133.313 us; speedup 1.0000x reference)
//
#include <hip/hip_runtime.h>
#include <math.h>

typedef float f32x4 __attribute__((ext_vector_type(4)));
typedef short bf16x8 __attribute__((ext_vector_type(8)));  // 8 bf16 in 4 VGPR

namespace {
constexpr int kB = 8, kL = 512, kD = 64, kS = 8;
constexpr int LP = 72;  // bf16 LDS row pad: 144B rows -> 2-way (free) on b128 frag reads
}

__device__ __forceinline__ unsigned short f2bf(float f) {      // RNE float->bf16 bits
    unsigned u = __float_as_uint(f);
    u += 0x7FFFu + ((u >> 16) & 1u);
    return (unsigned short)(u >> 16);
}
__device__ __forceinline__ unsigned pk2(float lo, float hi) {
    return (unsigned)f2bf(lo) | ((unsigned)f2bf(hi) << 16);
}

// B-fragment of W_s loaded DIRECTLY from global f32 W (row-major [d][e]).
// Element u of frag (ne,kb) for lane (fr,fh): W[s][kb*32+fh*8+u][ne*16+fr].
// Identical values to the old wt[e][d] path; L1/L2-hot (16 KB per s, shared by all blocks).
__device__ __forceinline__ void load_wb_direct(
    bf16x8 WB[4][2], const float* __restrict__ Wv, int s, int fr, int fh)
{
    const float* base = Wv + s * 4096 + fh * 8 * 64 + fr;
    #pragma unroll
    for (int ne = 0; ne < 4; ne++)
        #pragma unroll
        for (int kb = 0; kb < 2; kb++) {
            const float* p = base + kb * 32 * 64 + ne * 16;
            union { bf16x8 v; uint4 q; } cv;
            cv.q.x = pk2(p[0 * 64], p[1 * 64]);
            cv.q.y = pk2(p[2 * 64], p[3 * 64]);
            cv.q.z = pk2(p[4 * 64], p[5 * 64]);
            cv.q.w = pk2(p[6 * 64], p[7 * 64]);
            WB[ne][kb] = cv.v;
        }
}

// One s-iteration for one wave: T_s(32x64) -> private LDS -> rw(32x32) -> epilogue
__device__ __forceinline__ void grn_body(
    const bf16x8 WB[4][2], const bf16x8 A1[2][2], const bf16x8 Bf[2][2],
    unsigned short (*__restrict__ tsw)[LP], const float scl[4][kS][64],
    float oacc[2][2][4], int s, int fr, int fh, int wm, int wn,
    float us, float bgs)
{
    // T = x1 @ W_s : 2 mb x 4 ne tiles, K=64
    #pragma unroll
    for (int mb = 0; mb < 2; mb++)
        #pragma unroll
        for (int ne = 0; ne < 4; ne++) {
            f32x4 z = {0.f, 0.f, 0.f, 0.f};
            f32x4 t = __builtin_amdgcn_mfma_f32_16x16x32_bf16(A1[mb][0], WB[ne][0], z, 0, 0, 0);
            t = __builtin_amdgcn_mfma_f32_16x16x32_bf16(A1[mb][1], WB[ne][1], t, 0, 0, 0);
            #pragma unroll
            for (int r = 0; r < 4; r++)    // D: col=fr (e), row=fh*4+r (i)
                tsw[mb * 16 + fh * 4 + r][ne * 16 + fr] = f2bf(t[r]);
        }
    // rw = T @ x2^T  (A from private ts; in-wave lgkmcnt handles the RAW)
    bf16x8 At[2][2];
    #pragma unroll
    for (int mb = 0; mb < 2; mb++)
        #pragma unroll
        for (int kb = 0; kb < 2; kb++)
            At[mb][kb] = *(const bf16x8*)&tsw[mb * 16 + fr][fh * 8 + kb * 32];
    #pragma unroll
    for (int mb = 0; mb < 2; mb++)
        #pragma unroll
        for (int nb = 0; nb < 2; nb++) {
            f32x4 z = {0.f, 0.f, 0.f, 0.f};
            f32x4 acc = __builtin_amdgcn_mfma_f32_16x16x32_bf16(At[mb][0], Bf[nb][0], z, 0, 0, 0);
            acc = __builtin_amdgcn_mfma_f32_16x16x32_bf16(At[mb][1], Bf[nb][1], acc, 0, 0, 0);
            const int jj = wn * 32 + nb * 16 + fr;
            const float v2 = scl[2][s][jj], g2 = scl[3][s][jj];
            #pragma unroll
            for (int r = 0; r < 4; r++) {
                const int ii = wm * 32 + mb * 16 + fh * 4 + r;
                const float v1 = scl[0][s][ii], g1 = scl[1][s][ii];
                const float gate = 1.f / (1.f + __expf(-(g1 + g2 + bgs)));
                const float sv = 1.f / (1.f + __expf(-(v1 + v2)));
                const float res = fmaf(gate, acc[r] - sv, sv);  // gate*rw+(1-gate)*sv
                oacc[mb][nb][r] = fmaf(us, res, oacc[mb][nb][r]);
            }
        }
}

// ---------------- Single fused kernel: no workspace, no prep launch ----------------
__global__ __launch_bounds__(256, 2) void grn_one(
    const float* __restrict__ lstm1, const float* __restrict__ lstm2,
    const float* __restrict__ W, const float* __restrict__ V,
    const float* __restrict__ bS, const float* __restrict__ Wg,
    const float* __restrict__ bg, const float* __restrict__ u,
    float* __restrict__ out)
{
    const int jt = blockIdx.x, it = blockIdx.y, b = blockIdx.z;
    __shared__ __align__(16) unsigned short x1t[64][LP];
    __shared__ __align__(16) unsigned short x2t[64][LP];
    __shared__ __align__(16) unsigned short ts[4][32][LP];   // wave-private T scratch
    __shared__ float scl[4][kS][64];   // 0:v1(i) 1:g1(i) 2:v2(j) 3:g2(j)
    const int tid = threadIdx.x;
    {   // x1/x2 tiles f32 -> bf16 LDS
        const float* p1 = lstm1 + ((size_t)b * kL + it * 64) * kD;
        const float* p2 = lstm2 + ((size_t)b * kL + jt * 64) * kD;
        const int row = tid >> 2, c0 = (tid & 3) * 16;
        unsigned w1[8], w2[8];
        #pragma unroll
        for (int q = 0; q < 4; q++) {
            const float4 a = *(const float4*)(p1 + row * 64 + c0 + q * 4);
            const float4 c = *(const float4*)(p2 + row * 64 + c0 + q * 4);
            w1[q * 2] = pk2(a.x, a.y); w1[q * 2 + 1] = pk2(a.z, a.w);
            w2[q * 2] = pk2(c.x, c.y); w2[q * 2 + 1] = pk2(c.z, c.w);
        }
        uint4 a0 = {w1[0], w1[1], w1[2], w1[3]}, a1 = {w1[4], w1[5], w1[6], w1[7]};
        uint4 c0v = {w2[0], w2[1], w2[2], w2[3]}, c1 = {w2[4], w2[5], w2[6], w2[7]};
        *(uint4*)&x1t[row][c0] = a0; *(uint4*)&x1t[row][c0 + 8] = a1;
        *(uint4*)&x2t[row][c0] = c0v; *(uint4*)&x2t[row][c0 + 8] = c1;
    }
    {   // scl in-block: 256 threads = 4 kinds x 64 rows; f32 inputs from global (L2-hot)
        const int kind = tid >> 6, row = tid & 63;
        const float* xr = (kind < 2)
            ? (lstm1 + ((size_t)b * kL + it * 64 + row) * kD)
            : (lstm2 + ((size_t)b * kL + jt * 64 + row) * kD);
        float x[64];
        #pragma unroll
        for (int q = 0; q < 16; q++)
            *(float4*)&x[q * 4] = *(const float4*)(xr + q * 4);
        const float* vb = ((kind & 1) ? Wg : V) + ((kind & 2) ? kD : 0);
        #pragma unroll
        for (int s = 0; s < kS; s++) {
            const float* vec = vb + s * 2 * kD;
            float a = 0.f;
            #pragma unroll
            for (int q = 0; q < 16; q++) {
                const float4 vv = *(const float4*)(vec + q * 4);
                a = fmaf(vv.x, x[q * 4 + 0], a);
                a = fmaf(vv.y, x[q * 4 + 1], a);
                a = fmaf(vv.z, x[q * 4 + 2], a);
                a = fmaf(vv.w, x[q * 4 + 3], a);
            }
            scl[kind][s][row] = a;
        }
    }
    __syncthreads();   // the ONLY barrier
    const int lane = tid & 63, w = tid >> 6;
    const int wm = w >> 1, wn = w & 1;
    const int fr = lane & 15, fh = lane >> 4;
    unsigned short (*__restrict__ tsw)[LP] = ts[w];
    bf16x8 A1[2][2], Bf[2][2];
    #pragma unroll
    for (int mb = 0; mb < 2; mb++)
        #pragma unroll
        for (int kb = 0; kb < 2; kb++)
            A1[mb][kb] = *(const bf16x8*)&x1t[wm * 32 + mb * 16 + fr][fh * 8 + kb * 32];
    #pragma unroll
    for (int nb = 0; nb < 2; nb++)
        #pragma unroll
        for (int kb = 0; kb < 2; kb++)
            Bf[nb][kb] = *(const bf16x8*)&x2t[wn * 32 + nb * 16 + fr][fh * 8 + kb * 32];
    float bias_c = 0.f;
    #pragma unroll
    for (int s = 0; s < kS; s++) bias_c = fmaf(u[s], bS[s], bias_c);  // static s -> s_loads
    float oacc[2][2][4];
    #pragma unroll
    for (int mb = 0; mb < 2; mb++)
        #pragma unroll
        for (int nb = 0; nb < 2; nb++)
            #pragma unroll
            for (int r = 0; r < 4; r++) oacc[mb][nb][r] = bias_c;

    #pragma unroll 1
    for (int s = 0; s < kS; s++) {
        bf16x8 WB[4][2];
        load_wb_direct(WB, W, s, fr, fh);
        const float us = u[s], bgs = bg[s];   // uniform s -> scalar loads (no scratch)
        grn_body(WB, A1, Bf, tsw, scl, oacc, s, fr, fh, wm, wn, us, bgs);
    }
    float* op = out + ((size_t)b * kL + it * 64) * kL + jt * 64;
    #pragma unroll
    for (int mb = 0; mb < 2; mb++)
        #pragma unroll
        for (int nb = 0; nb < 2; nb++)
            #pragma unroll
            for (int r = 0; r < 4; r++)
                op[(wm * 32 + mb * 16 + fh * 4 + r) * kL + wn * 32 + nb * 16 + fr]
                    = oacc[mb][nb][r];
}

extern "C" void kernel_launch(void* const* d_in, const int* in_sizes, int n_in,
                              void* d_out, int out_size, void* d_ws, size_t ws_size,
                              hipStream_t stream) {
    const float* lstm1 = (const float*)d_in[0];
    const float* lstm2 = (const float*)d_in[1];
    const float* W     = (const float*)d_in[2];
    const float* V     = (const float*)d_in[3];
    const float* bS    = (const float*)d_in[4];
    const float* Wg    = (const float*)d_in[5];
    const float* bg    = (const float*)d_in[6];
    const float* u     = (const float*)d_in[7];
    grn_one<<<dim3(kL / 64, kL / 64, kB), 256, 0, stream>>>(
        lstm1, lstm2, W, V, bS, Wg, bg, u, (float*)d_out);
}

// Round 10
// 116.609 us; speedup vs baseline: 1.1432x; 1.1432x over previous
//
#include <hip/hip_runtime.h>
#include <math.h>

typedef float f32x4 __attribute__((ext_vector_type(4)));
typedef short bf16x8 __attribute__((ext_vector_type(8)));  // 8 bf16 in 4 VGPR

namespace {
constexpr int kB = 8, kL = 512, kD = 64, kS = 8;
// workspace layout (bytes)
constexpr size_t SCL_OFF = 0;                       // f32[4][8][8][512]  = 512 KB
constexpr size_t WT_OFF  = 524288;                  // bf16[8][64][64]    =  64 KB
constexpr size_t X1B_OFF = 589824;                  // bf16[8][512][64]   = 512 KB
constexpr size_t X2B_OFF = 1114112;                 // bf16[8][512][64]   = 512 KB
constexpr size_t T_OFF   = 1638400;                 // bf16[8][8][512][64]=   4 MB
}

__device__ __forceinline__ unsigned short f2bf(float f) {      // RNE float->bf16
    unsigned u = __float_as_uint(f);
    u += 0x7FFFu + ((u >> 16) & 1u);
    return (unsigned short)(u >> 16);
}
__device__ __forceinline__ unsigned pk2(float lo, float hi) {
    return (unsigned)f2bf(lo) | ((unsigned)f2bf(hi) << 16);
}

// ---- K1: wt (blocks 0..7) | scl dots (8..71) | x1b/x2b bf16 copies (72..103) ----
__global__ __launch_bounds__(256) void grn_prep(
    const float* __restrict__ lstm1, const float* __restrict__ lstm2,
    const float* __restrict__ W, const float* __restrict__ V,
    const float* __restrict__ Wg, unsigned char* __restrict__ ws)
{
    float* scl = (float*)(ws + SCL_OFF);
    unsigned short* wt = (unsigned short*)(ws + WT_OFF);
    const int tid = threadIdx.x;
    if (blockIdx.x < 8) {
        const int s = blockIdx.x;
        __shared__ float wsm[64][68];
        const float* pw = W + s * 4096;
        const int row = tid >> 2, c0 = (tid & 3) * 16;
        #pragma unroll
        for (int q = 0; q < 4; q++)
            *(float4*)&wsm[row][c0 + q * 4] = *(const float4*)(pw + row * 64 + c0 + q * 4);
        __syncthreads();
        // wt[s][e][d] = W[s][d][e]
        const int e = tid >> 2, d0 = (tid & 3) * 16;
        unsigned wd[8];
        #pragma unroll
        for (int q = 0; q < 8; q++)
            wd[q] = pk2(wsm[d0 + 2 * q][e], wsm[d0 + 2 * q + 1][e]);
        unsigned short* dst = wt + s * 4096 + e * 64 + d0;
        uint4 a = {wd[0], wd[1], wd[2], wd[3]};
        uint4 c = {wd[4], wd[5], wd[6], wd[7]};
        *(uint4*)(dst) = a;
        *(uint4*)(dst + 8) = c;
    } else if (blockIdx.x < 72) {
        const int rb = blockIdx.x - 8;
        const int b = rb >> 3, r0 = (rb & 7) * 64;
        const int kind = tid & 3, row = r0 + (tid >> 2);
        const float* x = (kind < 2 ? lstm1 : lstm2) + ((size_t)b * kL + row) * kD;
        float xr[64];
        #pragma unroll
        for (int q = 0; q < 16; q++)
            *(float4*)&xr[q * 4] = *(const float4*)(x + q * 4);
        const float* vb = ((kind & 1) ? Wg : V) + ((kind & 2) ? kD : 0);
        #pragma unroll
        for (int s = 0; s < kS; s++) {
            const float* vec = vb + s * 2 * kD;
            float a = 0.f;
            #pragma unroll
            for (int q = 0; q < 16; q++) {
                const float4 vv = *(const float4*)(vec + q * 4);
                a = fmaf(vv.x, xr[q * 4 + 0], a);
                a = fmaf(vv.y, xr[q * 4 + 1], a);
                a = fmaf(vv.z, xr[q * 4 + 2], a);
                a = fmaf(vv.w, xr[q * 4 + 3], a);
            }
            scl[(((size_t)kind * 8 + b) * 8 + s) * 512 + row] = a;
        }
    } else {
        const int t = blockIdx.x - 72;              // 0..31: 16 blocks each tensor
        const float* src = (t < 16) ? lstm1 : lstm2;
        unsigned short* dst = (unsigned short*)(ws + ((t < 16) ? X1B_OFF : X2B_OFF));
        const int tt = (t & 15) * 256 + tid;        // 0..4095
        #pragma unroll
        for (int k = 0; k < 8; k++) {
            const int c = tt + k * 4096;            // 8-float chunk id, 0..32767
            const float* p = src + (size_t)c * 8;
            const float4 a = *(const float4*)p;
            const float4 b2 = *(const float4*)(p + 4);
            uint4 o = {pk2(a.x, a.y), pk2(a.z, a.w), pk2(b2.x, b2.y), pk2(b2.z, b2.w)};
            *(uint4*)(dst + (size_t)c * 8) = o;
        }
    }
}

// ---- K2: T[b][s][i][e] = x1 @ W_s, one 16x64 slice per wave; no LDS, no barriers ----
__global__ __launch_bounds__(256) void grn_t2(unsigned char* __restrict__ ws)
{
    const unsigned short* wt  = (const unsigned short*)(ws + WT_OFF);
    const unsigned short* x1b = (const unsigned short*)(ws + X1B_OFF);
    unsigned short* T = (unsigned short*)(ws + T_OFF);
    const int g = blockIdx.x * 4 + (threadIdx.x >> 6);   // 0..2047
    const int b = g >> 8, rem = g & 255, s = rem >> 5, i16 = rem & 31;
    const int lane = threadIdx.x & 63, fr = lane & 15, fh = lane >> 4;
    // A frags: x1b[b][i0+fr][fh*8 + kb*32]  (coalesced 16B/lane)
    const unsigned short* ap = x1b + (((size_t)b * kL + i16 * 16 + fr) * kD + fh * 8);
    bf16x8 A0 = *(const bf16x8*)ap;
    bf16x8 A1 = *(const bf16x8*)(ap + 32);
    const unsigned short* bp = wt + (s * 4096 + fr * 64 + fh * 8);
    unsigned short* tp = T + (((size_t)(b * 8 + s)) * kL + i16 * 16) * kD;
    #pragma unroll
    for (int ne = 0; ne < 4; ne++) {
        const bf16x8 B0 = *(const bf16x8*)(bp + ne * 16 * 64);
        const bf16x8 B1 = *(const bf16x8*)(bp + ne * 16 * 64 + 32);
        f32x4 z = {0.f, 0.f, 0.f, 0.f};
        f32x4 t = __builtin_amdgcn_mfma_f32_16x16x32_bf16(A0, B0, z, 0, 0, 0);
        t = __builtin_amdgcn_mfma_f32_16x16x32_bf16(A1, B1, t, 0, 0, 0);
        #pragma unroll
        for (int r = 0; r < 4; r++)      // D: col=fr(e), row=fh*4+r(i)
            tp[(fh * 4 + r) * kD + ne * 16 + fr] = f2bf(t[r]);
    }
}

// ---- K3: one 16x16 output tile per wave; 8192 waves; no LDS, no barriers ----
__global__ __launch_bounds__(256) void grn_m3(
    const float* __restrict__ bS, const float* __restrict__ bg,
    const float* __restrict__ u, const unsigned char* __restrict__ ws,
    float* __restrict__ out)
{
    const float* scl = (const float*)(ws + SCL_OFF);
    const unsigned short* x2b = (const unsigned short*)(ws + X2B_OFF);
    const unsigned short* T = (const unsigned short*)(ws + T_OFF);
    const int g = blockIdx.x * 4 + (threadIdx.x >> 6);   // 0..8191
    const int b = g >> 10, rem = g & 1023, it = rem >> 5, jt = rem & 31;
    const int lane = threadIdx.x & 63, fr = lane & 15, fh = lane >> 4;
    const int i0 = it * 16, j0 = jt * 16;
    // B frags: x2b[b][j0+fr][fh*8 + kb*32]
    const unsigned short* bp = x2b + (((size_t)b * kL + j0 + fr) * kD + fh * 8);
    const bf16x8 Bf0 = *(const bf16x8*)bp;
    const bf16x8 Bf1 = *(const bf16x8*)(bp + 32);
    float bias_c = 0.f;
    #pragma unroll
    for (int s = 0; s < kS; s++) bias_c = fmaf(u[s], bS[s], bias_c);
    f32x4 oacc = {bias_c, bias_c, bias_c, bias_c};
    #pragma unroll
    for (int s = 0; s < kS; s++) {
        const unsigned short* ap = T + (((size_t)(b * 8 + s)) * kL + i0 + fr) * kD + fh * 8;
        const bf16x8 A0 = *(const bf16x8*)ap;
        const bf16x8 A1 = *(const bf16x8*)(ap + 32);
        f32x4 z = {0.f, 0.f, 0.f, 0.f};
        f32x4 acc = __builtin_amdgcn_mfma_f32_16x16x32_bf16(A0, Bf0, z, 0, 0, 0);
        acc = __builtin_amdgcn_mfma_f32_16x16x32_bf16(A1, Bf1, acc, 0, 0, 0);
        // scl: v1/g1 for rows i0+fh*4..+3 are one float4 each; v2/g2 per-lane dword
        const float4 v1q = *(const float4*)(scl + (((size_t)0 * 8 + b) * 8 + s) * 512 + i0 + fh * 4);
        const float4 g1q = *(const float4*)(scl + (((size_t)1 * 8 + b) * 8 + s) * 512 + i0 + fh * 4);
        const float v2 = scl[(((size_t)2 * 8 + b) * 8 + s) * 512 + j0 + fr];
        const float g2 = scl[(((size_t)3 * 8 + b) * 8 + s) * 512 + j0 + fr];
        const float us = u[s], bgs = bg[s];
        const float v1a[4] = {v1q.x, v1q.y, v1q.z, v1q.w};
        const float g1a[4] = {g1q.x, g1q.y, g1q.z, g1q.w};
        #pragma unroll
        for (int r = 0; r < 4; r++) {
            const float gate = 1.f / (1.f + __expf(-(g1a[r] + g2 + bgs)));
            const float sv = 1.f / (1.f + __expf(-(v1a[r] + v2)));
            const float res = fmaf(gate, acc[r] - sv, sv);   // gate*rw + (1-gate)*sv
            oacc[r] = fmaf(us, res, oacc[r]);
        }
    }
    float* op = out + (((size_t)b * kL + i0 + fh * 4) * kL + j0 + fr);
    #pragma unroll
    for (int r = 0; r < 4; r++)          // row i0+fh*4+r, col j0+fr (coalesced 64B segs)
        op[(size_t)r * kL] = oacc[r];
}

extern "C" void kernel_launch(void* const* d_in, const int* in_sizes, int n_in,
                              void* d_out, int out_size, void* d_ws, size_t ws_size,
                              hipStream_t stream) {
    const float* lstm1 = (const float*)d_in[0];
    const float* lstm2 = (const float*)d_in[1];
    const float* W     = (const float*)d_in[2];
    const float* V     = (const float*)d_in[3];
    const float* bS    = (const float*)d_in[4];
    const float* Wg    = (const float*)d_in[5];
    const float* bg    = (const float*)d_in[6];
    const float* u     = (const float*)d_in[7];
    unsigned char* ws = (unsigned char*)d_ws;   // uses ~5.6 MB; ws_size = 256 MiB
    grn_prep<<<104, 256, 0, stream>>>(lstm1, lstm2, W, V, Wg, ws);
    grn_t2<<<512, 256, 0, stream>>>(ws);
    grn_m3<<<2048, 256, 0, stream>>>(bS, bg, u, ws, (float*)d_out);
}

// Round 12
// 113.209 us; speedup vs baseline: 1.1776x; 1.0300x over previous
//
#include <hip/hip_runtime.h>
#include <math.h>

typedef float f32x4 __attribute__((ext_vector_type(4)));
typedef short bf16x8 __attribute__((ext_vector_type(8)));  // 8 bf16 in 4 VGPR

namespace {
constexpr int kB = 8, kL = 512, kD = 64, kS = 8;
// workspace layout (bytes)
constexpr size_t SCL_OFF = 0;                       // f32[4][8][8][512]  = 512 KB
constexpr size_t WT_OFF  = 524288;                  // bf16[8][64][64]    =  64 KB
constexpr size_t X1B_OFF = 589824;                  // bf16[8][512][64]   = 512 KB
constexpr size_t X2B_OFF = 1114112;                 // bf16[8][512][64]   = 512 KB
constexpr size_t T_OFF   = 1638400;                 // bf16[8][8][512][64]=   4 MB
}

__device__ __forceinline__ unsigned short f2bf(float f) {      // RNE float->bf16
    unsigned u = __float_as_uint(f);
    u += 0x7FFFu + ((u >> 16) & 1u);
    return (unsigned short)(u >> 16);
}
__device__ __forceinline__ unsigned pk2(float lo, float hi) {
    return (unsigned)f2bf(lo) | ((unsigned)f2bf(hi) << 16);
}

// ---- K1: wt (blocks 0..7) | EXP-form scl (8..71) | x1b/x2b bf16 copies (72..103) ----
// scl stores:  kind0: e^{-v1(i)}  kind1: e^{-(g1(i)+bg_s)}  kind2: e^{-v2(j)}  kind3: e^{-g2(j)}
// so K3's sigmoids become 1/(1+E1*E2) -- no exp in the hot loop.
__global__ __launch_bounds__(256) void grn_prep(
    const float* __restrict__ lstm1, const float* __restrict__ lstm2,
    const float* __restrict__ W, const float* __restrict__ V,
    const float* __restrict__ Wg, const float* __restrict__ bg,
    unsigned char* __restrict__ ws)
{
    float* scl = (float*)(ws + SCL_OFF);
    unsigned short* wt = (unsigned short*)(ws + WT_OFF);
    const int tid = threadIdx.x;
    if (blockIdx.x < 8) {
        const int s = blockIdx.x;
        __shared__ float wsm[64][68];
        const float* pw = W + s * 4096;
        const int row = tid >> 2, c0 = (tid & 3) * 16;
        #pragma unroll
        for (int q = 0; q < 4; q++)
            *(float4*)&wsm[row][c0 + q * 4] = *(const float4*)(pw + row * 64 + c0 + q * 4);
        __syncthreads();
        // wt[s][e][d] = W[s][d][e]
        const int e = tid >> 2, d0 = (tid & 3) * 16;
        unsigned wd[8];
        #pragma unroll
        for (int q = 0; q < 8; q++)
            wd[q] = pk2(wsm[d0 + 2 * q][e], wsm[d0 + 2 * q + 1][e]);
        unsigned short* dst = wt + s * 4096 + e * 64 + d0;
        uint4 a = {wd[0], wd[1], wd[2], wd[3]};
        uint4 c = {wd[4], wd[5], wd[6], wd[7]};
        *(uint4*)(dst) = a;
        *(uint4*)(dst + 8) = c;
    } else if (blockIdx.x < 72) {
        const int rb = blockIdx.x - 8;
        const int b = rb >> 3, r0 = (rb & 7) * 64;
        const int kind = tid & 3, row = r0 + (tid >> 2);
        const float* x = (kind < 2 ? lstm1 : lstm2) + ((size_t)b * kL + row) * kD;
        float xr[64];
        #pragma unroll
        for (int q = 0; q < 16; q++)
            *(float4*)&xr[q * 4] = *(const float4*)(x + q * 4);
        const float* vb = ((kind & 1) ? Wg : V) + ((kind & 2) ? kD : 0);
        #pragma unroll
        for (int s = 0; s < kS; s++) {
            const float* vec = vb + s * 2 * kD;
            float a = 0.f;
            #pragma unroll
            for (int q = 0; q < 16; q++) {
                const float4 vv = *(const float4*)(vec + q * 4);
                a = fmaf(vv.x, xr[q * 4 + 0], a);
                a = fmaf(vv.y, xr[q * 4 + 1], a);
                a = fmaf(vv.z, xr[q * 4 + 2], a);
                a = fmaf(vv.w, xr[q * 4 + 3], a);
            }
            const float badd = (kind == 1) ? bg[s] : 0.f;   // fold bg into E1g
            scl[(((size_t)kind * 8 + b) * 8 + s) * 512 + row] = __expf(-(a + badd));
        }
    } else {
        const int t = blockIdx.x - 72;              // 0..31: 16 blocks each tensor
        const float* src = (t < 16) ? lstm1 : lstm2;
        unsigned short* dst = (unsigned short*)(ws + ((t < 16) ? X1B_OFF : X2B_OFF));
        const int tt = (t & 15) * 256 + tid;        // 0..4095
        #pragma unroll
        for (int k = 0; k < 8; k++) {
            const int c = tt + k * 4096;            // 8-float chunk id, 0..32767
            const float* p = src + (size_t)c * 8;
            const float4 a = *(const float4*)p;
            const float4 b2 = *(const float4*)(p + 4);
            uint4 o = {pk2(a.x, a.y), pk2(a.z, a.w), pk2(b2.x, b2.y), pk2(b2.z, b2.w)};
            *(uint4*)(dst + (size_t)c * 8) = o;
        }
    }
}

// ---- K2: T[b][s][i][e] = x1 @ W_s, one 16x64 slice per wave; no LDS, no barriers ----
__global__ __launch_bounds__(256) void grn_t2(unsigned char* __restrict__ ws)
{
    const unsigned short* wt  = (const unsigned short*)(ws + WT_OFF);
    const unsigned short* x1b = (const unsigned short*)(ws + X1B_OFF);
    unsigned short* T = (unsigned short*)(ws + T_OFF);
    const int g = blockIdx.x * 4 + (threadIdx.x >> 6);   // 0..2047
    const int b = g >> 8, rem = g & 255, s = rem >> 5, i16 = rem & 31;
    const int lane = threadIdx.x & 63, fr = lane & 15, fh = lane >> 4;
    const unsigned short* ap = x1b + (((size_t)b * kL + i16 * 16 + fr) * kD + fh * 8);
    bf16x8 A0 = *(const bf16x8*)ap;
    bf16x8 A1 = *(const bf16x8*)(ap + 32);
    const unsigned short* bp = wt + (s * 4096 + fr * 64 + fh * 8);
    unsigned short* tp = T + (((size_t)(b * 8 + s)) * kL + i16 * 16) * kD;
    #pragma unroll
    for (int ne = 0; ne < 4; ne++) {
        const bf16x8 B0 = *(const bf16x8*)(bp + ne * 16 * 64);
        const bf16x8 B1 = *(const bf16x8*)(bp + ne * 16 * 64 + 32);
        f32x4 z = {0.f, 0.f, 0.f, 0.f};
        f32x4 t = __builtin_amdgcn_mfma_f32_16x16x32_bf16(A0, B0, z, 0, 0, 0);
        t = __builtin_amdgcn_mfma_f32_16x16x32_bf16(A1, B1, t, 0, 0, 0);
        #pragma unroll
        for (int r = 0; r < 4; r++)      // D: col=fr(e), row=fh*4+r(i)
            tp[(fh * 4 + r) * kD + ne * 16 + fr] = f2bf(t[r]);
    }
}

// ---- K3: one 16x16 output tile per wave; 8192 waves; exp-free epilogue, 1 rcp/slot ----
__global__ __launch_bounds__(256) void grn_m3(
    const float* __restrict__ bS, const float* __restrict__ u,
    const unsigned char* __restrict__ ws, float* __restrict__ out)
{
    const float* scl = (const float*)(ws + SCL_OFF);
    const unsigned short* x2b = (const unsigned short*)(ws + X2B_OFF);
    const unsigned short* T = (const unsigned short*)(ws + T_OFF);
    const int g = blockIdx.x * 4 + (threadIdx.x >> 6);   // 0..8191
    const int b = g >> 10, rem = g & 1023, it = rem >> 5, jt = rem & 31;
    const int lane = threadIdx.x & 63, fr = lane & 15, fh = lane >> 4;
    const int i0 = it * 16, j0 = jt * 16;
    const unsigned short* bp = x2b + (((size_t)b * kL + j0 + fr) * kD + fh * 8);
    const bf16x8 Bf0 = *(const bf16x8*)bp;
    const bf16x8 Bf1 = *(const bf16x8*)(bp + 32);
    float bias_c = 0.f;
    #pragma unroll
    for (int s = 0; s < kS; s++) bias_c = fmaf(u[s], bS[s], bias_c);
    f32x4 oacc = {bias_c, bias_c, bias_c, bias_c};
    #pragma unroll
    for (int s = 0; s < kS; s++) {
        const unsigned short* ap = T + (((size_t)(b * 8 + s)) * kL + i0 + fr) * kD + fh * 8;
        const bf16x8 A0 = *(const bf16x8*)ap;
        const bf16x8 A1 = *(const bf16x8*)(ap + 32);
        f32x4 z = {0.f, 0.f, 0.f, 0.f};
        f32x4 acc = __builtin_amdgcn_mfma_f32_16x16x32_bf16(A0, Bf0, z, 0, 0, 0);
        acc = __builtin_amdgcn_mfma_f32_16x16x32_bf16(A1, Bf1, acc, 0, 0, 0);
        // per-row exponentials: E1v/E1g for rows i0+fh*4..+3 (float4), E2v/E2g per-lane j
        const float4 E1vq = *(const float4*)(scl + (((size_t)0 * 8 + b) * 8 + s) * 512 + i0 + fh * 4);
        const float4 E1gq = *(const float4*)(scl + (((size_t)1 * 8 + b) * 8 + s) * 512 + i0 + fh * 4);
        const float E2v = scl[(((size_t)2 * 8 + b) * 8 + s) * 512 + j0 + fr];
        const float E2g = scl[(((size_t)3 * 8 + b) * 8 + s) * 512 + j0 + fr];
        const float us = u[s];
        const float E1va[4] = {E1vq.x, E1vq.y, E1vq.z, E1vq.w};
        const float E1ga[4] = {E1gq.x, E1gq.y, E1gq.z, E1gq.w};
        #pragma unroll
        for (int r = 0; r < 4; r++) {
            const float dg = fmaf(E1ga[r], E2g, 1.f);        // 1 + e^{-(g1+g2+bg)}
            const float dv = fmaf(E1va[r], E2v, 1.f);        // 1 + e^{-(v1+v2)}
            const float rp = __builtin_amdgcn_rcpf(dg * dv); // one rcp for both sigmoids
            const float gate = dv * rp;                      // 1/dg
            const float sv   = dg * rp;                      // 1/dv
            const float res = fmaf(gate, acc[r] - sv, sv);   // gate*rw + (1-gate)*sv
            oacc[r] = fmaf(us, res, oacc[r]);
        }
    }
    float* op = out + (((size_t)b * kL + i0 + fh * 4) * kL + j0 + fr);
    #pragma unroll
    for (int r = 0; r < 4; r++)          // row i0+fh*4+r, col j0+fr (coalesced 64B segs)
        op[(size_t)r * kL] = oacc[r];
}

extern "C" void kernel_launch(void* const* d_in, const int* in_sizes, int n_in,
                              void* d_out, int out_size, void* d_ws, size_t ws_size,
                              hipStream_t stream) {
    const float* lstm1 = (const float*)d_in[0];
    const float* lstm2 = (const float*)d_in[1];
    const float* W     = (const float*)d_in[2];
    const float* V     = (const float*)d_in[3];
    const float* bS    = (const float*)d_in[4];
    const float* Wg    = (const float*)d_in[5];
    const float* bg    = (const float*)d_in[6];
    const float* u     = (const float*)d_in[7];
    unsigned char* ws = (unsigned char*)d_ws;   // uses ~5.6 MB; ws_size = 256 MiB
    grn_prep<<<104, 256, 0, stream>>>(lstm1, lstm2, W, V, Wg, bg, ws);
    grn_t2<<<512, 256, 0, stream>>>(ws);
    grn_m3<<<2048, 256, 0, stream>>>(bS, u, ws, (float*)d_out);
}

// Round 13
// 105.188 us; speedup vs baseline: 1.2674x; 1.0763x over previous
//
#include <hip/hip_runtime.h>
#include <math.h>

typedef float f32x4 __attribute__((ext_vector_type(4)));
typedef short bf16x8 __attribute__((ext_vector_type(8)));  // 8 bf16 in 4 VGPR

namespace {
constexpr int kB = 8, kL = 512, kD = 64, kS = 8;
// workspace layout (bytes)
constexpr size_t SCL_OFF = 0;                       // f32[4][8][8][512]  = 512 KB
constexpr size_t T_OFF   = 524288;                  // bf16[8][8][512][64]=   4 MB
}

__device__ __forceinline__ unsigned short f2bf(float f) {      // RNE float->bf16
    unsigned u = __float_as_uint(f);
    u += 0x7FFFu + ((u >> 16) & 1u);
    return (unsigned short)(u >> 16);
}
__device__ __forceinline__ unsigned pk2(float lo, float hi) {
    return (unsigned)f2bf(lo) | ((unsigned)f2bf(hi) << 16);
}
// load 8 consecutive f32 at p, convert to one bf16x8 A/B fragment
__device__ __forceinline__ bf16x8 ldcvt8(const float* __restrict__ p) {
    const float4 a = *(const float4*)p;
    const float4 b = *(const float4*)(p + 4);
    union { bf16x8 v; uint4 q; } cv;
    cv.q.x = pk2(a.x, a.y); cv.q.y = pk2(a.z, a.w);
    cv.q.z = pk2(b.x, b.y); cv.q.w = pk2(b.z, b.w);
    return cv.v;
}

// ---- K_A: blocks 0..63 EXP-form scl | blocks 64..575 T-build (self-contained W transpose)
// scl: kind0 e^{-v1(i)} | kind1 e^{-(g1(i)+bg_s)} | kind2 e^{-v2(j)} | kind3 e^{-g2(j)}
__global__ __launch_bounds__(256) void grn_a(
    const float* __restrict__ lstm1, const float* __restrict__ lstm2,
    const float* __restrict__ W, const float* __restrict__ V,
    const float* __restrict__ Wg, const float* __restrict__ bg,
    unsigned char* __restrict__ ws)
{
    __shared__ float wsm[64][68];                       // W_s staging (f32)
    __shared__ __align__(16) unsigned short tls[4][16][72];  // per-wave D staging
    float* scl = (float*)(ws + SCL_OFF);
    unsigned short* T = (unsigned short*)(ws + T_OFF);
    const int tid = threadIdx.x;
    if (blockIdx.x < 64) {
        const int rb = blockIdx.x;
        const int b = rb >> 3, r0 = (rb & 7) * 64;
        const int kind = tid & 3, row = r0 + (tid >> 2);
        const float* x = (kind < 2 ? lstm1 : lstm2) + ((size_t)b * kL + row) * kD;
        float xr[64];
        #pragma unroll
        for (int q = 0; q < 16; q++)
            *(float4*)&xr[q * 4] = *(const float4*)(x + q * 4);
        const float* vb = ((kind & 1) ? Wg : V) + ((kind & 2) ? kD : 0);
        #pragma unroll
        for (int s = 0; s < kS; s++) {
            const float* vec = vb + s * 2 * kD;
            float a = 0.f;
            #pragma unroll
            for (int q = 0; q < 16; q++) {
                const float4 vv = *(const float4*)(vec + q * 4);
                a = fmaf(vv.x, xr[q * 4 + 0], a);
                a = fmaf(vv.y, xr[q * 4 + 1], a);
                a = fmaf(vv.z, xr[q * 4 + 2], a);
                a = fmaf(vv.w, xr[q * 4 + 3], a);
            }
            const float badd = (kind == 1) ? bg[s] : 0.f;
            scl[(((size_t)kind * 8 + b) * 8 + s) * 512 + row] = __expf(-(a + badd));
        }
        return;
    }
    // ---- T-build: block = (b, s, i64); 4 waves x 16 i-rows x full e ----
    const int t = blockIdx.x - 64;
    const int b = t >> 6, rem = t & 63, s = rem >> 3, i64 = rem & 7;
    {   // stage W_s f32 coalesced
        const float* pw = W + s * 4096;
        const int row = tid >> 2, c0 = (tid & 3) * 16;
        #pragma unroll
        for (int q = 0; q < 4; q++)
            *(float4*)&wsm[row][c0 + q * 4] = *(const float4*)(pw + row * 64 + c0 + q * 4);
    }
    __syncthreads();
    const int lane = tid & 63, w = tid >> 6;
    const int fr = lane & 15, fh = lane >> 4;
    const int i0 = i64 * 64 + w * 16;
    // A frags from lstm1 f32 (rows i0+fr, cols fh*8 + kb*32)
    const float* ap = lstm1 + (((size_t)b * kL + i0 + fr) * kD + fh * 8);
    const bf16x8 A0 = ldcvt8(ap);
    const bf16x8 A1 = ldcvt8(ap + 32);
    // B frags from wsm: element u -> W[kb*32+fh*8+u][ne*16+fr]
    unsigned short (*__restrict__ tw)[72] = tls[w];
    #pragma unroll
    for (int ne = 0; ne < 4; ne++) {
        union { bf16x8 v; uint4 q; } B0, B1;
        const int e = ne * 16 + fr;
        B0.q.x = pk2(wsm[fh * 8 + 0][e], wsm[fh * 8 + 1][e]);
        B0.q.y = pk2(wsm[fh * 8 + 2][e], wsm[fh * 8 + 3][e]);
        B0.q.z = pk2(wsm[fh * 8 + 4][e], wsm[fh * 8 + 5][e]);
        B0.q.w = pk2(wsm[fh * 8 + 6][e], wsm[fh * 8 + 7][e]);
        B1.q.x = pk2(wsm[32 + fh * 8 + 0][e], wsm[32 + fh * 8 + 1][e]);
        B1.q.y = pk2(wsm[32 + fh * 8 + 2][e], wsm[32 + fh * 8 + 3][e]);
        B1.q.z = pk2(wsm[32 + fh * 8 + 4][e], wsm[32 + fh * 8 + 5][e]);
        B1.q.w = pk2(wsm[32 + fh * 8 + 6][e], wsm[32 + fh * 8 + 7][e]);
        f32x4 z = {0.f, 0.f, 0.f, 0.f};
        f32x4 d = __builtin_amdgcn_mfma_f32_16x16x32_bf16(A0, B0.v, z, 0, 0, 0);
        d = __builtin_amdgcn_mfma_f32_16x16x32_bf16(A1, B1.v, d, 0, 0, 0);
        #pragma unroll
        for (int r = 0; r < 4; r++)      // D: col=fr(e), row=fh*4+r(i) -> wave-private LDS
            tw[fh * 4 + r][ne * 16 + fr] = f2bf(d[r]);
    }
    // read back coalesced (in-wave RAW -> lgkmcnt) and store T rows as uint4
    const int rr = lane >> 2, cc = (lane & 3) * 16;
    const uint4 q0 = *(const uint4*)&tw[rr][cc];
    const uint4 q1 = *(const uint4*)&tw[rr][cc + 8];
    unsigned short* tp = T + (((size_t)(b * 8 + s)) * kL + i0 + rr) * kD + cc;
    *(uint4*)tp = q0;
    *(uint4*)(tp + 8) = q1;
}

// ---- K_B: one 16x32 output tile per wave; 4096 waves; exp-free epilogue ----
__global__ __launch_bounds__(256) void grn_b(
    const float* __restrict__ lstm2, const float* __restrict__ bS,
    const float* __restrict__ u, const unsigned char* __restrict__ ws,
    float* __restrict__ out)
{
    const float* scl = (const float*)(ws + SCL_OFF);
    const unsigned short* T = (const unsigned short*)(ws + T_OFF);
    const int g = blockIdx.x * 4 + (threadIdx.x >> 6);   // 0..4095
    const int b = g >> 9, rem = g & 511, it = rem >> 4, j32 = rem & 15;
    const int lane = threadIdx.x & 63, fr = lane & 15, fh = lane >> 4;
    const int i0 = it * 16, j0 = j32 * 32;
    // B frags for two j16 tiles, converted from f32 lstm2
    bf16x8 Bf[2][2];
    #pragma unroll
    for (int jj = 0; jj < 2; jj++) {
        const float* bp = lstm2 + (((size_t)b * kL + j0 + jj * 16 + fr) * kD + fh * 8);
        Bf[jj][0] = ldcvt8(bp);
        Bf[jj][1] = ldcvt8(bp + 32);
    }
    float bias_c = 0.f;
    #pragma unroll
    for (int s = 0; s < kS; s++) bias_c = fmaf(u[s], bS[s], bias_c);
    f32x4 oacc[2];
    oacc[0] = f32x4{bias_c, bias_c, bias_c, bias_c};
    oacc[1] = oacc[0];
    #pragma unroll
    for (int s = 0; s < kS; s++) {
        const unsigned short* ap = T + (((size_t)(b * 8 + s)) * kL + i0 + fr) * kD + fh * 8;
        const bf16x8 A0 = *(const bf16x8*)ap;
        const bf16x8 A1 = *(const bf16x8*)(ap + 32);
        const float4 E1vq = *(const float4*)(scl + (((size_t)0 * 8 + b) * 8 + s) * 512 + i0 + fh * 4);
        const float4 E1gq = *(const float4*)(scl + (((size_t)1 * 8 + b) * 8 + s) * 512 + i0 + fh * 4);
        const float us = u[s];
        const float E1va[4] = {E1vq.x, E1vq.y, E1vq.z, E1vq.w};
        const float E1ga[4] = {E1gq.x, E1gq.y, E1gq.z, E1gq.w};
        #pragma unroll
        for (int jj = 0; jj < 2; jj++) {
            f32x4 z = {0.f, 0.f, 0.f, 0.f};
            f32x4 acc = __builtin_amdgcn_mfma_f32_16x16x32_bf16(A0, Bf[jj][0], z, 0, 0, 0);
            acc = __builtin_amdgcn_mfma_f32_16x16x32_bf16(A1, Bf[jj][1], acc, 0, 0, 0);
            const int j = j0 + jj * 16 + fr;
            const float E2v = scl[(((size_t)2 * 8 + b) * 8 + s) * 512 + j];
            const float E2g = scl[(((size_t)3 * 8 + b) * 8 + s) * 512 + j];
            #pragma unroll
            for (int r = 0; r < 4; r++) {
                const float dg = fmaf(E1ga[r], E2g, 1.f);
                const float dv = fmaf(E1va[r], E2v, 1.f);
                const float rp = __builtin_amdgcn_rcpf(dg * dv);
                const float gate = dv * rp;                  // sigmoid(g1+g2+bg)
                const float sv   = dg * rp;                  // sigmoid(v1+v2)
                const float res = fmaf(gate, acc[r] - sv, sv);
                oacc[jj][r] = fmaf(us, res, oacc[jj][r]);
            }
        }
    }
    #pragma unroll
    for (int jj = 0; jj < 2; jj++) {
        float* op = out + (((size_t)b * kL + i0 + fh * 4) * kL + j0 + jj * 16 + fr);
        #pragma unroll
        for (int r = 0; r < 4; r++)
            op[(size_t)r * kL] = oacc[jj][r];
    }
}

extern "C" void kernel_launch(void* const* d_in, const int* in_sizes, int n_in,
                              void* d_out, int out_size, void* d_ws, size_t ws_size,
                              hipStream_t stream) {
    const float* lstm1 = (const float*)d_in[0];
    const float* lstm2 = (const float*)d_in[1];
    const float* W     = (const float*)d_in[2];
    const float* V     = (const float*)d_in[3];
    const float* bS    = (const float*)d_in[4];
    const float* Wg    = (const float*)d_in[5];
    const float* bg    = (const float*)d_in[6];
    const float* u     = (const float*)d_in[7];
    unsigned char* ws = (unsigned char*)d_ws;   // uses 4.5 MB; ws_size = 256 MiB
    grn_a<<<576, 256, 0, stream>>>(lstm1, lstm2, W, V, Wg, bg, ws);
    grn_b<<<1024, 256, 0, stream>>>(lstm2, bS, u, ws, (float*)d_out);
}